// Round 9
// baseline (418.316 us; speedup 1.0000x reference)
//
#include <hip/hip_runtime.h>
#include <hip/hip_bf16.h>

#define NB 16
#define NHD 16
#define ND 1024
#define NLK 4096
#define NFF 2048

typedef float f32x4 __attribute__((ext_vector_type(4)));
typedef float f32x2 __attribute__((ext_vector_type(2)));
typedef __bf16 bf16x2v __attribute__((ext_vector_type(2)));
typedef __bf16 bf16x4v __attribute__((ext_vector_type(4)));
typedef __bf16 bf16x8 __attribute__((ext_vector_type(8)));

// ---------------- k_fill: diagnostic if ws too small ----------------
__global__ void k_fill(float* out, int n, float v) {
  int i = blockIdx.x * 256 + threadIdx.x;
  if (i < n) out[i] = v;
}

// ---------------- grid barrier: arrive-counter (1 poller) + release-flag ----------------
__device__ __forceinline__ void gbar(unsigned* bar, int slot, unsigned nblk) {
  unsigned* ctr = &bar[slot * 32];
  unsigned* flg = &bar[512 + slot * 32];
  __syncthreads();
  if (threadIdx.x == 0) {
    __hip_atomic_fetch_add(ctr, 1u, __ATOMIC_RELEASE, __HIP_MEMORY_SCOPE_AGENT);
    if (blockIdx.x == 0) {
      while (__hip_atomic_load(ctr, __ATOMIC_RELAXED, __HIP_MEMORY_SCOPE_AGENT) < nblk)
        __builtin_amdgcn_s_sleep(8);
      __hip_atomic_store(flg, 1u, __ATOMIC_RELEASE, __HIP_MEMORY_SCOPE_AGENT);
    } else {
      while (__hip_atomic_load(flg, __ATOMIC_RELAXED, __HIP_MEMORY_SCOPE_AGENT) == 0)
        __builtin_amdgcn_s_sleep(8);
    }
    __builtin_amdgcn_fence(__ATOMIC_ACQUIRE, "agent");
  }
  __syncthreads();
}

// ---------------- k_mega: whole block in one kernel, 512 blocks x 512 threads ----------------
__global__ __launch_bounds__(512, 4) void k_mega(
    const float* __restrict__ query, const float* __restrict__ key,
    const int* __restrict__ mask, const float* __restrict__ Wq,
    const float* __restrict__ bq, const float* __restrict__ Wk,
    const float* __restrict__ bk, const float* __restrict__ Wv,
    const float* __restrict__ bv, const float* __restrict__ Wo,
    const float* __restrict__ bo, const float* __restrict__ raw_thr,
    const float* __restrict__ Wvp, const float* __restrict__ W1,
    const float* __restrict__ b1, const float* __restrict__ W2,
    const float* __restrict__ b2, const float* __restrict__ g1,
    const float* __restrict__ be1, const float* __restrict__ g2,
    const float* __restrict__ be2,
    float* __restrict__ Qrow, float* __restrict__ cvec, float* __restrict__ attn_x,
    float* __restrict__ r1, float* __restrict__ h1, float* __restrict__ out2,
    float* __restrict__ s0, float* __restrict__ mloc, float* __restrict__ lloc,
    __hip_bfloat16* __restrict__ t_bf, __hip_bfloat16* __restrict__ u_bf,
    __hip_bfloat16* __restrict__ wvpt, __hip_bfloat16* __restrict__ pu,
    float* __restrict__ outp, unsigned* __restrict__ bar) {
  __shared__ __align__(16) unsigned char arena[79360];
  float* af = (float*)arena;
  int blk = blockIdx.x, t = threadIdx.x;
  int wv = t >> 6, lane = t & 63, l15 = lane & 15, g4 = lane >> 4;
  int half = t >> 8, vt = t & 255;

  // ======== P0: zero atomic-accumulator buffers ========
  {
    int g = blk * 512 + t;
    if (g < 16384) {
      Qrow[g] = 0.f;
      cvec[g] = 0.f;
      attn_x[g] = 0.f;
      r1[g] = 0.f;
      out2[g] = 0.f;
    }
    if (g < 32768) h1[g] = 0.f;
  }
  gbar(bar, 0, 512);

  // ======== P1: k0a (blk<128) | k0t (blk 128..191) ========
  if (blk < 128) {
    int which = blk >> 6;
    int jb = (blk >> 5) & 1;
    int i0c = blk & 31;
    int i0 = i0c * 32;
    int j = jb * 512 + t;
    if (t < 128) {
      int e = t * 4;
      int b = e >> 5, ii = e & 31;
      float4 v = *(const float4*)(query + (size_t)b * ND + i0 + ii);
      af[ii * 20 + b] = v.x;
      af[(ii + 1) * 20 + b] = v.y;
      af[(ii + 2) * 20 + b] = v.z;
      af[(ii + 3) * 20 + b] = v.w;
    }
    __syncthreads();
    float acc[16];
#pragma unroll
    for (int q = 0; q < 16; ++q) acc[q] = 0.f;
    for (int ii = 0; ii < 32; ++ii) {
      int i = i0 + ii;
      float wvv = which ? Wvp[(size_t)(ND + i) * ND + j] : Wq[(size_t)i * ND + j];
      float qv[16];
      const float4* qp = (const float4*)&af[ii * 20];
      *(float4*)&qv[0] = qp[0];
      *(float4*)&qv[4] = qp[1];
      *(float4*)&qv[8] = qp[2];
      *(float4*)&qv[12] = qp[3];
#pragma unroll
      for (int q = 0; q < 16; ++q) acc[q] += wvv * qv[q];
    }
    float* out = which ? cvec : Qrow;
    float bias = (!which && i0c == 0) ? bq[j] : 0.f;
#pragma unroll
    for (int q = 0; q < 16; ++q) atomicAdd(&out[q * ND + j], acc[q] + bias);
  } else if (blk < 192) {
    int tb = blk - 128;  // 0..63
    int n0 = (tb & 15) * 64;
    int k0base = (tb >> 4) * 256;
    for (int it = 0; it < 4; ++it) {
      int k0 = k0base + it * 64;
#pragma unroll
      for (int i = 0; i < 2; ++i) {
        int idx = t * 4 + i * 2048;
        int kk = idx >> 6, nn = idx & 63;
        float4 v = *(const float4*)(Wvp + (size_t)(k0 + kk) * ND + n0 + nn);
        af[kk * 68 + nn] = v.x;
        af[kk * 68 + nn + 1] = v.y;
        af[kk * 68 + nn + 2] = v.z;
        af[kk * 68 + nn + 3] = v.w;
      }
      __syncthreads();
#pragma unroll
      for (int i = 0; i < 2; ++i) {
        int idx = t * 4 + i * 2048;
        int nn = idx >> 6, kk = idx & 63;
        bf16x4v o;
#pragma unroll
        for (int jj = 0; jj < 4; ++jj) o[jj] = (__bf16)af[(kk + jj) * 68 + nn];
        *(bf16x4v*)((__bf16*)wvpt + (size_t)(n0 + nn) * ND + k0 + kk) = o;
      }
      __syncthreads();
    }
  }
  gbar(bar, 1, 512);

  // ======== P2: k0b — t_bf[b][h][d], s0 (blk<64, 2 units/block) ========
  if (blk < 64) {
    int h = blk & 15;
    int dblk = (blk >> 4) * 2 + half;  // 0..7
    float* pm = af + half * 9472;
    float* qs = pm;           // [16][64]
    float* wks = pm + 1024;   // [128][66]
    {
      int lin = vt * 4;
      int bb = lin >> 6, dk = lin & 63;
      *(float4*)&qs[bb * 64 + dk] = *(const float4*)(Qrow + bb * ND + h * 64 + dk);
    }
#pragma unroll
    for (int e = 0; e < 8; ++e) {
      int l2 = e * 1024 + vt * 4;
      int d = l2 >> 6, dk2 = l2 & 63;
      *(float4*)&wks[d * 66 + dk2] =
          *(const float4*)(Wk + (size_t)(dblk * 128 + d) * ND + h * 64 + dk2);
    }
    __syncthreads();
    if (dblk == 0 && vt < 16) {
      float a = 0.f;
      const float* bkh = bk + h * 64;
      for (int jj = 0; jj < 64; ++jj) a += bkh[jj] * qs[vt * 64 + jj];
      s0[vt * 16 + h] = a;
    }
    int d = vt >> 1, bh = (vt & 1) * 8;
    float acc[8];
#pragma unroll
    for (int q = 0; q < 8; ++q) acc[q] = 0.f;
    for (int dk = 0; dk < 64; ++dk) {
      float wvv = wks[d * 66 + dk];
#pragma unroll
      for (int q = 0; q < 8; ++q) acc[q] += wvv * qs[(bh + q) * 64 + dk];
    }
#pragma unroll
    for (int q = 0; q < 8; ++q)
      t_bf[(size_t)((bh + q) * 16 + h) * ND + dblk * 128 + d] = (__hip_bfloat16)acc[q];
  }
  gbar(bar, 2, 512);

  // ======== P3: flash — all 512 blocks; b = blk>>5, ch = blk&31 ========
  {
    int ch = blk & 31, b = blk >> 5;
    __bf16* kstage = (__bf16*)arena;         // [8][32][128] chunk-XOR swizzled
    __bf16* psb = (__bf16*)(arena + 65536);  // [8][32][18]
    float* scr = (float*)(arena + 74752);    // [32][17]
    float* wls = (float*)(arena + 76928);    // [32][16]
    float* sm = (float*)(arena + 78976);
    float* mrun = sm;
    float* lrun = sm + 16;
    float* fact = sm + 32;
    float* mnewv = sm + 48;
    float* thv = sm + 64;
    float* s0v = sm + 80;

    f32x2 pu_r[16];
#pragma unroll
    for (int h = 0; h < 16; ++h) pu_r[h] = (f32x2){0.f, 0.f};
    if (t < 16) {
      mrun[t] = -1.0e9f;
      lrun[t] = 0.f;
      thv[t] = log1pf(expf(raw_thr[t]));
      s0v[t] = s0[b * 16 + t];
    }
    __syncthreads();
    const float* keyb = key + (size_t)b * NLK * ND;
    const __hip_bfloat16* tb = t_bf + (size_t)(b * 16 + l15) * ND;
    int dsl = wv * 128;
    __bf16* kst_w = kstage + wv * 4096;
    int kk = t >> 4, hh = t & 15;
    int c16 = lane >> 2, bofs = (lane & 3) * 2;
    for (int sp = 0; sp < 4; ++sp) {
      int ks0 = ch * 128 + sp * 32;
      f32x4 sa0 = {0.f, 0.f, 0.f, 0.f}, sa1 = {0.f, 0.f, 0.f, 0.f};
#pragma unroll
      for (int st = 0; st < 4; ++st) {
        int d = dsl + st * 32 + g4 * 8;
        bf16x8 bfr = *(const bf16x8*)(tb + d);
        const float* a0p = keyb + (size_t)(ks0 + l15) * ND + d;
        const float* a1p = a0p + (size_t)16 * ND;
        float a0[8], a1[8];
        *(float4*)&a0[0] = *(const float4*)a0p;
        *(float4*)&a0[4] = *(const float4*)(a0p + 4);
        *(float4*)&a1[0] = *(const float4*)a1p;
        *(float4*)&a1[4] = *(const float4*)(a1p + 4);
        bf16x8 af0, af1;
#pragma unroll
        for (int j = 0; j < 8; ++j) {
          af0[j] = (__bf16)a0[j];
          af1[j] = (__bf16)a1[j];
        }
        int pos = (((st * 4 + g4) ^ l15) & 15) * 8;
        *(bf16x8*)(kst_w + l15 * 128 + pos) = af0;
        *(bf16x8*)(kst_w + (16 + l15) * 128 + pos) = af1;
        sa0 = __builtin_amdgcn_mfma_f32_16x16x32_bf16(af0, bfr, sa0, 0, 0, 0);
        sa1 = __builtin_amdgcn_mfma_f32_16x16x32_bf16(af1, bfr, sa1, 0, 0, 0);
      }
#pragma unroll
      for (int r = 0; r < 4; ++r) {
        psb[(wv * 32 + g4 * 4 + r) * 18 + l15] = (__bf16)sa0[r];
        psb[(wv * 32 + 16 + g4 * 4 + r) * 18 + l15] = (__bf16)sa1[r];
      }
      __syncthreads();  // A
      float sum = 0.f;
#pragma unroll
      for (int w = 0; w < 8; ++w) sum += (float)psb[(w * 32 + kk) * 18 + hh];
      float sc_ = (sum + s0v[hh]) * 0.125f;
      int mv = mask[b * NLK + ks0 + kk];
      float sv = (mv != 0 && sc_ > thv[hh]) ? sc_ : -1.0e9f;
      scr[kk * 17 + hh] = sv;
      __syncthreads();  // B
      if (wv == 0) {
        float m = -3.4e38f;
#pragma unroll
        for (int j = 0; j < 8; ++j) m = fmaxf(m, scr[(g4 * 8 + j) * 17 + l15]);
        m = fmaxf(m, __shfl_xor(m, 16, 64));
        m = fmaxf(m, __shfl_xor(m, 32, 64));
        if (lane < 16) {
          float mn = fmaxf(mrun[lane], m);
          mnewv[lane] = mn;
          fact[lane] = expf(mrun[lane] - mn);
          mrun[lane] = mn;
        }
      }
      __syncthreads();  // C
      float w = expf(sv - mnewv[hh]);
      scr[kk * 17 + hh] = w;
      wls[kk * 16 + hh] = w;
      __syncthreads();  // D
      if (wv == 0) {
        float s = 0.f;
#pragma unroll
        for (int j = 0; j < 8; ++j) s += scr[(g4 * 8 + j) * 17 + l15];
        s += __shfl_xor(s, 16, 64);
        s += __shfl_xor(s, 32, 64);
        if (lane < 16) lrun[lane] = lrun[lane] * fact[lane] + s;
      }
#pragma unroll
      for (int h = 0; h < 16; ++h) pu_r[h] *= fact[h];
      for (int k = 0; k < 32; ++k) {
        int phys = ((c16 ^ k) & 15) * 8;
        unsigned u = *(const unsigned*)(kst_w + k * 128 + phys + bofs);
        f32x2 kv;
        kv[0] = __uint_as_float(u << 16);
        kv[1] = __uint_as_float(u & 0xffff0000u);
        const f32x4* wr = (const f32x4*)&wls[k * 16];
        f32x4 w0 = wr[0], w1 = wr[1], w2 = wr[2], w3 = wr[3];
#pragma unroll
        for (int q = 0; q < 4; ++q) {
          pu_r[q] += w0[q] * kv;
          pu_r[4 + q] += w1[q] * kv;
          pu_r[8 + q] += w2[q] * kv;
          pu_r[12 + q] += w3[q] * kv;
        }
      }
    }
    int dlane = dsl + lane * 2;
    size_t pubase = (size_t)((b * 32 + ch) * 16) * ND + dlane;
#pragma unroll
    for (int h = 0; h < 16; ++h) {
      bf16x2v o;
      o[0] = (__bf16)pu_r[h][0];
      o[1] = (__bf16)pu_r[h][1];
      *(bf16x2v*)((__bf16*)pu + pubase + (size_t)h * ND) = o;
    }
    if (t < 16) {
      mloc[(b * 32 + ch) * 16 + t] = mrun[t];
      lloc[(b * 32 + ch) * 16 + t] = lrun[t];
    }
  }
  gbar(bar, 3, 512);

  // ======== P4: U — u_bf = combine(pu) (blk<128, 2 units/block) ========
  if (blk < 128) {
    int unit = blk * 2 + half;  // 0..255
    int b = unit >> 4, h = unit & 15;
    float* sc = af + half * 32;
    if (vt < 32) {
      float m = mloc[(b * 32 + vt) * 16 + h];
      float l = lloc[(b * 32 + vt) * 16 + h];
      float mg = m;
      for (int o = 16; o > 0; o >>= 1) mg = fmaxf(mg, __shfl_xor(mg, o, 32));
      float term = l * expf(m - mg);
      float ls = term;
      for (int o = 16; o > 0; o >>= 1) ls += __shfl_xor(ls, o, 32);
      sc[vt] = expf(m - mg) / ls;
    }
    __syncthreads();
    int d = vt * 4;
    f32x4 acc = {0.f, 0.f, 0.f, 0.f};
    for (int c = 0; c < 32; ++c) {
      bf16x4v v4 = *(const bf16x4v*)((const __bf16*)pu +
                                     (size_t)((b * 32 + c) * 16 + h) * ND + d);
      f32x4 v = {(float)v4[0], (float)v4[1], (float)v4[2], (float)v4[3]};
      acc += sc[c] * v;
    }
    bf16x4v o;
#pragma unroll
    for (int j = 0; j < 4; ++j) o[j] = (__bf16)acc[j];
    *(bf16x4v*)((__bf16*)u_bf + (size_t)(b * 16 + h) * ND + d) = o;
  }
  gbar(bar, 4, 512);

  // ======== P5: ZAX — z-tile MFMA + cvec, ·Wv -> attn_x (blk<128, 2 units of 4 waves) ========
  if (blk < 128) {
    int uu = blk * 2 + half;  // half == wv>>2
    int h = uu >> 4, d0 = (uu & 15) * 64;
    int wv2 = wv & 3;
    float* vb = af + half * 1088;  // [16][68]
    const __hip_bfloat16* ub = u_bf + (size_t)(l15 * 16 + h) * ND;
    const __hip_bfloat16* wb = wvpt + (size_t)(d0 + wv2 * 16 + l15) * ND;
    f32x4 acc = {0.f, 0.f, 0.f, 0.f};
    for (int ks = 0; ks < 32; ++ks) {
      int d = ks * 32 + g4 * 8;
      bf16x8 a = *(const bf16x8*)(ub + d);
      bf16x8 bb = *(const bf16x8*)(wb + d);
      acc = __builtin_amdgcn_mfma_f32_16x16x32_bf16(a, bb, acc, 0, 0, 0);
    }
#pragma unroll
    for (int r = 0; r < 4; ++r) {
      int b = g4 * 4 + r;
      int nn = wv2 * 16 + l15;
      vb[b * 68 + nn] = acc[r] + cvec[(size_t)b * ND + d0 + nn];
    }
    __syncthreads();
    int joff = vt & 63, bg = vt >> 6;
    int j = h * 64 + joff;
    float ax[4] = {0.f, 0.f, 0.f, 0.f};
    for (int dd = 0; dd < 64; ++dd) {
      float wv_ = Wv[(size_t)(d0 + dd) * ND + j];
#pragma unroll
      for (int q = 0; q < 4; ++q) ax[q] += wv_ * vb[(bg * 4 + q) * 68 + dd];
    }
#pragma unroll
    for (int q = 0; q < 4; ++q) {
      float val = ax[q];
      if ((uu & 15) == 0) val += bv[j];
      atomicAdd(&attn_x[(size_t)(bg * 4 + q) * ND + j], val);
    }
  }
  gbar(bar, 5, 512);

  // ======== P6: R1 = query + attn_x@Wo + bo (blk<64, 2 units) ========
  if (blk < 64) {
    int unit = blk * 2 + half;  // 0..127
    int j0 = (unit & 7) * 128;
    int d0 = (unit >> 3) * 64;
    float* ax = af + half * 1088;
    {
      int lin = vt * 4;
      int bb = lin >> 6, dd = lin & 63;
      *(float4*)&ax[bb * 68 + dd] = *(const float4*)(attn_x + (size_t)bb * ND + d0 + dd);
    }
    __syncthreads();
    int joff = vt & 127, bg = vt >> 7;
    int j = j0 + joff;
    float acc[8];
#pragma unroll
    for (int q = 0; q < 8; ++q) acc[q] = 0.f;
    for (int dd = 0; dd < 64; ++dd) {
      float wv_ = Wo[(size_t)(d0 + dd) * ND + j];
#pragma unroll
      for (int q = 0; q < 8; ++q) acc[q] += wv_ * ax[(bg * 8 + q) * 68 + dd];
    }
#pragma unroll
    for (int q = 0; q < 8; ++q) {
      int bb = bg * 8 + q;
      float val = acc[q];
      if ((unit >> 3) == 0) val += bo[j] + query[(size_t)bb * ND + j];
      atomicAdd(&r1[(size_t)bb * ND + j], val);
    }
  }
  gbar(bar, 6, 512);

  // ======== P7: FF1 — h1 = LN1(r1)@W1 (blk<64, 2 units) ========
  if (blk < 64) {
    int unit = blk * 2 + half;
    int n = (unit & 7) * 256 + vt;
    int d0 = (unit >> 3) * 64;
    float* base = af + half * 2048;
    float* xs = base;            // [16][68]
    float* mv_s = base + 1984;
    float* iv_s = base + 2000;
    {
      int row = vt >> 4, seg = vt & 15;
      float s = 0.f, s2 = 0.f;
      const float* rp = r1 + (size_t)row * ND + seg * 64;
      for (int q = 0; q < 16; ++q) {
        float4 v = *(const float4*)(rp + q * 4);
        s += v.x + v.y + v.z + v.w;
        s2 += v.x * v.x + v.y * v.y + v.z * v.z + v.w * v.w;
      }
      for (int o = 1; o < 16; o <<= 1) {
        s += __shfl_xor(s, o, 16);
        s2 += __shfl_xor(s2, o, 16);
      }
      if (seg == 0) {
        float mean = s * (1.f / ND);
        float var = s2 * (1.f / ND) - mean * mean;
        mv_s[row] = mean;
        iv_s[row] = rsqrtf(var + 1e-5f);
      }
    }
    __syncthreads();
    {
      int e = vt * 4;
      int bb = e >> 6, dd = e & 63;
      float4 v = *(const float4*)(r1 + (size_t)bb * ND + d0 + dd);
      float4 g = *(const float4*)(g1 + d0 + dd);
      float4 be = *(const float4*)(be1 + d0 + dd);
      float m = mv_s[bb], iv = iv_s[bb];
      xs[bb * 68 + dd] = (v.x - m) * iv * g.x + be.x;
      xs[bb * 68 + dd + 1] = (v.y - m) * iv * g.y + be.y;
      xs[bb * 68 + dd + 2] = (v.z - m) * iv * g.z + be.z;
      xs[bb * 68 + dd + 3] = (v.w - m) * iv * g.w + be.w;
    }
    __syncthreads();
    float acc[16];
#pragma unroll
    for (int q = 0; q < 16; ++q) acc[q] = 0.f;
    for (int dd = 0; dd < 64; ++dd) {
      float wv_ = W1[(size_t)(d0 + dd) * NFF + n];
#pragma unroll
      for (int q = 0; q < 16; ++q) acc[q] += wv_ * xs[q * 68 + dd];
    }
#pragma unroll
    for (int q = 0; q < 16; ++q) atomicAdd(&h1[(size_t)q * NFF + n], acc[q]);
  }
  gbar(bar, 7, 512);

  // ======== P8: FF2 — out2 = relu(h1+b1)@W2 (blk<64, 2 units) ========
  if (blk < 64) {
    int unit = blk * 2 + half;
    int j0 = (unit & 7) * 128;
    int n0 = (unit >> 3) * 128;
    float* hs = af + half * 2112;  // [16][132]
#pragma unroll
    for (int e = 0; e < 8; ++e) {
      int lin = e * 256 + vt;
      int bb = lin >> 7, nn = lin & 127;
      float hv = h1[(size_t)bb * NFF + n0 + nn] + b1[n0 + nn];
      hs[bb * 132 + nn] = fmaxf(hv, 0.f);
    }
    __syncthreads();
    int joff = vt & 127, bg = vt >> 7;
    int j = j0 + joff;
    float acc[8];
#pragma unroll
    for (int q = 0; q < 8; ++q) acc[q] = 0.f;
    for (int nn = 0; nn < 128; ++nn) {
      float wv_ = W2[(size_t)(n0 + nn) * ND + j];
#pragma unroll
      for (int q = 0; q < 8; ++q) acc[q] += wv_ * hs[(bg * 8 + q) * 132 + nn];
    }
#pragma unroll
    for (int q = 0; q < 8; ++q) atomicAdd(&out2[(size_t)(bg * 8 + q) * ND + j], acc[q]);
  }
  gbar(bar, 8, 512);

  // ======== P9: LN2 — out = LN( LN1(r1) + out2 + b2 ) (blk<8, 2 units) ========
  if (blk < 8) {
    int b = blk * 2 + half;  // 0..15
    float* base = af + half * 1024;
    float* rs = base;
    float* rs2 = base + 256;
    float4 v = *(const float4*)(r1 + (size_t)b * ND + vt * 4);
    float s = v.x + v.y + v.z + v.w;
    float s2 = v.x * v.x + v.y * v.y + v.z * v.z + v.w * v.w;
    rs[vt] = s;
    rs2[vt] = s2;
    __syncthreads();
    for (int st = 128; st > 0; st >>= 1) {
      if (vt < st) {
        rs[vt] += rs[vt + st];
        rs2[vt] += rs2[vt + st];
      }
      __syncthreads();
    }
    float mean = rs[0] * (1.f / ND);
    float var = rs2[0] * (1.f / ND) - mean * mean;
    float inv = rsqrtf(var + 1e-5f);
    float4 g = *(const float4*)(g1 + vt * 4);
    float4 be = *(const float4*)(be1 + vt * 4);
    float4 o2 = *(const float4*)(out2 + (size_t)b * ND + vt * 4);
    float4 bb2 = *(const float4*)(b2 + vt * 4);
    float4 v2;
    v2.x = (v.x - mean) * inv * g.x + be.x + o2.x + bb2.x;
    v2.y = (v.y - mean) * inv * g.y + be.y + o2.y + bb2.y;
    v2.z = (v.z - mean) * inv * g.z + be.z + o2.z + bb2.z;
    v2.w = (v.w - mean) * inv * g.w + be.w + o2.w + bb2.w;
    __syncthreads();
    s = v2.x + v2.y + v2.z + v2.w;
    s2 = v2.x * v2.x + v2.y * v2.y + v2.z * v2.z + v2.w * v2.w;
    rs[vt] = s;
    rs2[vt] = s2;
    __syncthreads();
    for (int st = 128; st > 0; st >>= 1) {
      if (vt < st) {
        rs[vt] += rs[vt + st];
        rs2[vt] += rs2[vt + st];
      }
      __syncthreads();
    }
    float mean2 = rs[0] * (1.f / ND);
    float var2 = rs2[0] * (1.f / ND) - mean2 * mean2;
    float inv2 = rsqrtf(var2 + 1e-5f);
    float4 gg = *(const float4*)(g2 + vt * 4);
    float4 bbe = *(const float4*)(be2 + vt * 4);
    float4 o;
    o.x = (v2.x - mean2) * inv2 * gg.x + bbe.x;
    o.y = (v2.y - mean2) * inv2 * gg.y + bbe.y;
    o.z = (v2.z - mean2) * inv2 * gg.z + bbe.z;
    o.w = (v2.w - mean2) * inv2 * gg.w + bbe.w;
    *(float4*)(outp + (size_t)b * ND + vt * 4) = o;
  }
}

extern "C" void kernel_launch(void* const* d_in, const int* in_sizes, int n_in,
                              void* d_out, int out_size, void* d_ws, size_t ws_size,
                              hipStream_t stream) {
  const float* query = (const float*)d_in[0];
  const float* key = (const float*)d_in[1];
  const int* mask = (const int*)d_in[2];
  const float* Wq = (const float*)d_in[3];
  const float* bq = (const float*)d_in[4];
  const float* Wk = (const float*)d_in[5];
  const float* bk = (const float*)d_in[6];
  const float* Wv = (const float*)d_in[7];
  const float* bv = (const float*)d_in[8];
  const float* Wo = (const float*)d_in[9];
  const float* bo = (const float*)d_in[10];
  const float* raw_thr = (const float*)d_in[11];
  const float* Wvp = (const float*)d_in[12];
  const float* W1 = (const float*)d_in[13];
  const float* b1 = (const float*)d_in[14];
  const float* W2 = (const float*)d_in[15];
  const float* b2 = (const float*)d_in[16];
  const float* g1 = (const float*)d_in[17];
  const float* be1 = (const float*)d_in[18];
  const float* g2 = (const float*)d_in[19];
  const float* be2 = (const float*)d_in[20];

  // workspace layout (bytes)
  const size_t OFF_BAR = 0;          // 4K (zeroed)
  const size_t ZERO_BYTES = 4096;
  const size_t OFF_QROW = 4096;      // 64K (zeroed in-kernel P0)
  const size_t OFF_C = 69632;        // 64K (P0)
  const size_t OFF_ATTNX = 135168;   // 64K (P0)
  const size_t OFF_R1 = 200704;      // 64K (P0)
  const size_t OFF_H1 = 266240;      // 128K (P0)
  const size_t OFF_OUT2 = 397312;    // 64K (P0)
  const size_t OFF_S0 = 462848;      // 1K
  const size_t OFF_MLOC = 463872;    // 32K
  const size_t OFF_LLOC = 496640;    // 32K
  const size_t OFF_TBF = 529408;     // 512K bf16
  const size_t OFF_UBF = 1053696;    // 512K bf16
  const size_t OFF_WVPT = 1577984;   // 2M bf16
  const size_t OFF_PU = 3675136;     // 16M bf16
  const size_t TOTAL = 20452352;

  if (ws_size < TOTAL) {
    k_fill<<<dim3((out_size + 255) / 256), dim3(256), 0, stream>>>((float*)d_out, out_size,
                                                                   12345.0f);
    return;
  }

  char* wsb = (char*)d_ws;
  unsigned* bar = (unsigned*)(wsb + OFF_BAR);
  float* Qrow = (float*)(wsb + OFF_QROW);
  float* cvec = (float*)(wsb + OFF_C);
  float* attn_x = (float*)(wsb + OFF_ATTNX);
  float* r1 = (float*)(wsb + OFF_R1);
  float* h1 = (float*)(wsb + OFF_H1);
  float* out2 = (float*)(wsb + OFF_OUT2);
  float* s0 = (float*)(wsb + OFF_S0);
  float* mloc = (float*)(wsb + OFF_MLOC);
  float* lloc = (float*)(wsb + OFF_LLOC);
  __hip_bfloat16* t_bf = (__hip_bfloat16*)(wsb + OFF_TBF);
  __hip_bfloat16* u_bf = (__hip_bfloat16*)(wsb + OFF_UBF);
  __hip_bfloat16* wvpt = (__hip_bfloat16*)(wsb + OFF_WVPT);
  __hip_bfloat16* pu = (__hip_bfloat16*)(wsb + OFF_PU);

  hipMemsetAsync(d_ws, 0, ZERO_BYTES, stream);

  k_mega<<<dim3(512), dim3(512), 0, stream>>>(
      query, key, mask, Wq, bq, Wk, bk, Wv, bv, Wo, bo, raw_thr, Wvp, W1, b1, W2, b2,
      g1, be1, g2, be2, Qrow, cvec, attn_x, r1, h1, out2, s0, mloc, lloc, t_bf, u_bf,
      wvpt, pu, (float*)d_out, bar);
}

// Round 11
// 191.581 us; speedup vs baseline: 2.1835x; 2.1835x over previous
//
#include <hip/hip_runtime.h>
#include <hip/hip_bf16.h>

#define NB 16
#define NHD 16
#define ND 1024
#define NLK 4096
#define NFF 2048

typedef float f32x4 __attribute__((ext_vector_type(4)));
typedef float f32x2 __attribute__((ext_vector_type(2)));
typedef __bf16 bf16x2v __attribute__((ext_vector_type(2)));
typedef __bf16 bf16x4v __attribute__((ext_vector_type(4)));
typedef __bf16 bf16x8 __attribute__((ext_vector_type(8)));

// ---------------- k_fill: diagnostic if ws too small ----------------
__global__ void k_fill(float* out, int n, float v) {
  int i = blockIdx.x * 256 + threadIdx.x;
  if (i < n) out[i] = v;
}

// ---------------- grid barrier: arrive-counter (1 poller) + release-flag ----------------
__device__ __forceinline__ void gbar(unsigned* ctr, unsigned* flg, unsigned nblk) {
  __syncthreads();
  if (threadIdx.x == 0) {
    __hip_atomic_fetch_add(ctr, 1u, __ATOMIC_RELEASE, __HIP_MEMORY_SCOPE_AGENT);
    if (blockIdx.x == 0) {
      while (__hip_atomic_load(ctr, __ATOMIC_RELAXED, __HIP_MEMORY_SCOPE_AGENT) < nblk)
        __builtin_amdgcn_s_sleep(8);
      __hip_atomic_store(flg, 1u, __ATOMIC_RELEASE, __HIP_MEMORY_SCOPE_AGENT);
    } else {
      while (__hip_atomic_load(flg, __ATOMIC_RELAXED, __HIP_MEMORY_SCOPE_AGENT) == 0)
        __builtin_amdgcn_s_sleep(8);
    }
    __builtin_amdgcn_fence(__ATOMIC_ACQUIRE, "agent");
  }
  __syncthreads();
}

// ---------------- k_pre: {k0a: Qrow,cvec | k0t: wvpt} -> gbar -> k0b: t_bf, s0 ----------------
__global__ __launch_bounds__(256) void k_pre(const float* __restrict__ Wq,
                                             const float* __restrict__ bq,
                                             const float* __restrict__ Wvp,
                                             const float* __restrict__ query,
                                             const float* __restrict__ Wk,
                                             const float* __restrict__ bk,
                                             float* __restrict__ Qrow,
                                             float* __restrict__ cvec,
                                             __hip_bfloat16* __restrict__ wvpt,
                                             __hip_bfloat16* __restrict__ t_bf,
                                             float* __restrict__ s0,
                                             unsigned* __restrict__ bar) {
  __shared__ float pmem[9472];
  int blk = blockIdx.x;
  int t = threadIdx.x;
  // ======== phase 1 ========
  if (blk < 128) {
    int which = blk >> 6;
    int jb = blk & 3;
    int i0 = ((blk >> 2) & 15) * 64;
    int j = jb * 256 + t;
    {
      int e = t * 4;
      int b = e >> 6, ii = e & 63;
      float4 v = *(const float4*)(query + (size_t)b * ND + i0 + ii);
      pmem[ii * 20 + b] = v.x;
      pmem[(ii + 1) * 20 + b] = v.y;
      pmem[(ii + 2) * 20 + b] = v.z;
      pmem[(ii + 3) * 20 + b] = v.w;
    }
    __syncthreads();
    float acc[16];
#pragma unroll
    for (int q = 0; q < 16; ++q) acc[q] = 0.f;
    for (int ii = 0; ii < 64; ++ii) {
      int i = i0 + ii;
      float wv = which ? Wvp[(size_t)(ND + i) * ND + j] : Wq[(size_t)i * ND + j];
      float qv[16];
      const float4* qp = (const float4*)&pmem[ii * 20];
      *(float4*)&qv[0] = qp[0];
      *(float4*)&qv[4] = qp[1];
      *(float4*)&qv[8] = qp[2];
      *(float4*)&qv[12] = qp[3];
#pragma unroll
      for (int q = 0; q < 16; ++q) acc[q] += wv * qv[q];
    }
    float* out = which ? cvec : Qrow;
    float bias = (!which && i0 == 0) ? bq[j] : 0.f;
#pragma unroll
    for (int q = 0; q < 16; ++q) atomicAdd(&out[q * ND + j], acc[q] + bias);
  } else {
    int tb = blk - 128;  // 0..63
    int n0 = (tb & 15) * 64;
    int k0base = (tb >> 4) * 256;
    for (int it = 0; it < 4; ++it) {
      int k0 = k0base + it * 64;
#pragma unroll
      for (int i = 0; i < 4; ++i) {
        int idx = t * 4 + i * 1024;
        int kk = idx >> 6, nn = idx & 63;
        float4 v = *(const float4*)(Wvp + (size_t)(k0 + kk) * ND + n0 + nn);
        pmem[kk * 68 + nn] = v.x;
        pmem[kk * 68 + nn + 1] = v.y;
        pmem[kk * 68 + nn + 2] = v.z;
        pmem[kk * 68 + nn + 3] = v.w;
      }
      __syncthreads();
#pragma unroll
      for (int i = 0; i < 4; ++i) {
        int idx = t * 4 + i * 1024;
        int nn = idx >> 6, kk = idx & 63;
        bf16x4v o;
#pragma unroll
        for (int j = 0; j < 4; ++j) o[j] = (__bf16)pmem[(kk + j) * 68 + nn];
        *(bf16x4v*)((__bf16*)wvpt + (size_t)(n0 + nn) * ND + k0 + kk) = o;
      }
      __syncthreads();
    }
  }
  gbar(&bar[5 * 32], &bar[256 + 5 * 32], 192);
  // ======== phase 2: k0b on blk<128 ========
  {
    int h = blk & 15, dblk = blk >> 4;
    float* qs = pmem;
    float* wks = pmem + 1024;
    if (blk < 128) {
      int lin = t * 4;
      int bb = lin >> 6, dk = lin & 63;
      *(float4*)&qs[bb * 64 + dk] = *(const float4*)(Qrow + bb * ND + h * 64 + dk);
#pragma unroll
      for (int e = 0; e < 8; ++e) {
        int l2 = e * 1024 + t * 4;
        int d = l2 >> 6, dk2 = l2 & 63;
        *(float4*)&wks[d * 66 + dk2] =
            *(const float4*)(Wk + (size_t)(dblk * 128 + d) * ND + h * 64 + dk2);
      }
    }
    __syncthreads();
    if (blk < 128) {
      if (dblk == 0 && t < 16) {
        float a = 0.f;
        const float* bkh = bk + h * 64;
        for (int jj = 0; jj < 64; ++jj) a += bkh[jj] * qs[t * 64 + jj];
        s0[t * 16 + h] = a;
      }
      int d = t >> 1, bh = (t & 1) * 8;
      float acc[8];
#pragma unroll
      for (int q = 0; q < 8; ++q) acc[q] = 0.f;
      for (int dk = 0; dk < 64; ++dk) {
        float wv = wks[d * 66 + dk];
#pragma unroll
        for (int q = 0; q < 8; ++q) acc[q] += wv * qs[(bh + q) * 64 + dk];
      }
#pragma unroll
      for (int q = 0; q < 8; ++q)
        t_bf[(size_t)((bh + q) * 16 + h) * ND + dblk * 128 + d] = (__hip_bfloat16)acc[q];
    }
  }
}

// ---------------- k_flash: 8-wave, key read ONCE, LDS-staged bf16 key, VALU PV ----------------
__global__ __launch_bounds__(512, 4) void k_flash(const float* __restrict__ key,
                                                  const __hip_bfloat16* __restrict__ t_bf,
                                                  const float* __restrict__ s0,
                                                  const float* __restrict__ raw_thr,
                                                  const int* __restrict__ mask,
                                                  __hip_bfloat16* __restrict__ pu,
                                                  float* __restrict__ mloc,
                                                  float* __restrict__ lloc) {
  int ch = blockIdx.x, b = blockIdx.y;
  int t = threadIdx.x;
  int wv = t >> 6, lane = t & 63, l15 = lane & 15, g4 = lane >> 4;
  __shared__ __align__(16) unsigned char lds_arena[79360];
  __bf16* kstage = (__bf16*)lds_arena;         // [8][32][128] chunk-XOR swizzled
  __bf16* psb = (__bf16*)(lds_arena + 65536);  // [8][32][18]
  float* scr = (float*)(lds_arena + 74752);    // [32][17]
  float* wls = (float*)(lds_arena + 76928);    // [32][16]
  float* sm = (float*)(lds_arena + 78976);
  float* mrun = sm;
  float* lrun = sm + 16;
  float* fact = sm + 32;
  float* mnewv = sm + 48;
  float* thv = sm + 64;
  float* s0v = sm + 80;

  f32x2 pu_r[16];
#pragma unroll
  for (int h = 0; h < 16; ++h) pu_r[h] = (f32x2){0.f, 0.f};
  if (t < 16) {
    mrun[t] = -1.0e9f;
    lrun[t] = 0.f;
    thv[t] = log1pf(expf(raw_thr[t]));
    s0v[t] = s0[b * 16 + t];
  }
  __syncthreads();
  const float* keyb = key + (size_t)b * NLK * ND;
  const __hip_bfloat16* tb = t_bf + (size_t)(b * 16 + l15) * ND;
  int dsl = wv * 128;
  __bf16* kst_w = kstage + wv * 4096;
  int kk = t >> 4, hh = t & 15;
  int c16 = lane >> 2, bofs = (lane & 3) * 2;
  for (int sp = 0; sp < 4; ++sp) {
    int ks0 = ch * 128 + sp * 32;
    f32x4 sa0 = {0.f, 0.f, 0.f, 0.f}, sa1 = {0.f, 0.f, 0.f, 0.f};
#pragma unroll
    for (int st = 0; st < 4; ++st) {
      int d = dsl + st * 32 + g4 * 8;
      bf16x8 bfr = *(const bf16x8*)(tb + d);
      const float* a0p = keyb + (size_t)(ks0 + l15) * ND + d;
      const float* a1p = a0p + (size_t)16 * ND;
      float a0[8], a1[8];
      *(float4*)&a0[0] = *(const float4*)a0p;
      *(float4*)&a0[4] = *(const float4*)(a0p + 4);
      *(float4*)&a1[0] = *(const float4*)a1p;
      *(float4*)&a1[4] = *(const float4*)(a1p + 4);
      bf16x8 af0, af1;
#pragma unroll
      for (int j = 0; j < 8; ++j) {
        af0[j] = (__bf16)a0[j];
        af1[j] = (__bf16)a1[j];
      }
      int pos = (((st * 4 + g4) ^ l15) & 15) * 8;
      *(bf16x8*)(kst_w + l15 * 128 + pos) = af0;
      *(bf16x8*)(kst_w + (16 + l15) * 128 + pos) = af1;
      sa0 = __builtin_amdgcn_mfma_f32_16x16x32_bf16(af0, bfr, sa0, 0, 0, 0);
      sa1 = __builtin_amdgcn_mfma_f32_16x16x32_bf16(af1, bfr, sa1, 0, 0, 0);
    }
#pragma unroll
    for (int r = 0; r < 4; ++r) {
      psb[(wv * 32 + g4 * 4 + r) * 18 + l15] = (__bf16)sa0[r];
      psb[(wv * 32 + 16 + g4 * 4 + r) * 18 + l15] = (__bf16)sa1[r];
    }
    __syncthreads();  // A
    float sum = 0.f;
#pragma unroll
    for (int w = 0; w < 8; ++w) sum += (float)psb[(w * 32 + kk) * 18 + hh];
    float sc_ = (sum + s0v[hh]) * 0.125f;
    int mv = mask[b * NLK + ks0 + kk];
    float sv = (mv != 0 && sc_ > thv[hh]) ? sc_ : -1.0e9f;
    scr[kk * 17 + hh] = sv;
    __syncthreads();  // B
    if (wv == 0) {
      float m = -3.4e38f;
#pragma unroll
      for (int j = 0; j < 8; ++j) m = fmaxf(m, scr[(g4 * 8 + j) * 17 + l15]);
      m = fmaxf(m, __shfl_xor(m, 16, 64));
      m = fmaxf(m, __shfl_xor(m, 32, 64));
      if (lane < 16) {
        float mn = fmaxf(mrun[lane], m);
        mnewv[lane] = mn;
        fact[lane] = expf(mrun[lane] - mn);
        mrun[lane] = mn;
      }
    }
    __syncthreads();  // C
    float w = expf(sv - mnewv[hh]);
    scr[kk * 17 + hh] = w;
    wls[kk * 16 + hh] = w;
    __syncthreads();  // D
    if (wv == 0) {
      float s = 0.f;
#pragma unroll
      for (int j = 0; j < 8; ++j) s += scr[(g4 * 8 + j) * 17 + l15];
      s += __shfl_xor(s, 16, 64);
      s += __shfl_xor(s, 32, 64);
      if (lane < 16) lrun[lane] = lrun[lane] * fact[lane] + s;
    }
#pragma unroll
    for (int h = 0; h < 16; ++h) pu_r[h] *= fact[h];
    for (int k = 0; k < 32; ++k) {
      int phys = ((c16 ^ k) & 15) * 8;
      unsigned u = *(const unsigned*)(kst_w + k * 128 + phys + bofs);
      f32x2 kv;
      kv[0] = __uint_as_float(u << 16);
      kv[1] = __uint_as_float(u & 0xffff0000u);
      const f32x4* wr = (const f32x4*)&wls[k * 16];
      f32x4 w0 = wr[0], w1 = wr[1], w2 = wr[2], w3 = wr[3];
#pragma unroll
      for (int q = 0; q < 4; ++q) {
        pu_r[q] += w0[q] * kv;
        pu_r[4 + q] += w1[q] * kv;
        pu_r[8 + q] += w2[q] * kv;
        pu_r[12 + q] += w3[q] * kv;
      }
    }
  }
  int dlane = dsl + lane * 2;
  size_t pubase = (size_t)((b * 32 + ch) * 16) * ND + dlane;
#pragma unroll
  for (int h = 0; h < 16; ++h) {
    bf16x2v o;
    o[0] = (__bf16)pu_r[h][0];
    o[1] = (__bf16)pu_r[h][1];
    *(bf16x2v*)((__bf16*)pu + pubase + (size_t)h * ND) = o;
  }
  if (t < 16) {
    mloc[(b * 32 + ch) * 16 + t] = mrun[t];
    lloc[(b * 32 + ch) * 16 + t] = lrun[t];
  }
}

// ---------------- k_tail: 256 blocks; ured -> ZAX -> r1 -> ff1 -> ff2 -> ln2 ----------------
__global__ __launch_bounds__(256, 2) void k_tail(
    const __hip_bfloat16* __restrict__ pu, const float* __restrict__ mloc,
    const float* __restrict__ lloc, __hip_bfloat16* __restrict__ u_bf,
    const __hip_bfloat16* __restrict__ wvpt,
    const float* __restrict__ cvec, const float* __restrict__ Wv,
    const float* __restrict__ bv, float* __restrict__ attn_x,
    const float* __restrict__ Wo, const float* __restrict__ bo,
    const float* __restrict__ query, float* __restrict__ r1,
    const float* __restrict__ g1, const float* __restrict__ be1,
    const float* __restrict__ W1, float* __restrict__ h1,
    const float* __restrict__ b1, const float* __restrict__ W2,
    float* __restrict__ out2, const float* __restrict__ b2,
    const float* __restrict__ g2, const float* __restrict__ be2,
    float* __restrict__ outp, unsigned* __restrict__ bar) {
  __shared__ float smf[2176];
  int blk = blockIdx.x, t = threadIdx.x;
  int wv = t >> 6, lane = t & 63, l15 = lane & 15, g4 = lane >> 4;

  // ======== phase U: u_bf = combine(pu) ; zero accumulators ========
  {
    int g = blk * 256 + t;
    if (g < 16384) {
      attn_x[g] = 0.f;
      r1[g] = 0.f;
      out2[g] = 0.f;
    }
    if (g < 32768) h1[g] = 0.f;
    int b = blk >> 4, h = blk & 15;
    if (t < 32) {
      float m = mloc[(b * 32 + t) * 16 + h];
      float l = lloc[(b * 32 + t) * 16 + h];
      float mg = m;
      for (int o = 16; o > 0; o >>= 1) mg = fmaxf(mg, __shfl_xor(mg, o, 32));
      float term = l * expf(m - mg);
      float ls = term;
      for (int o = 16; o > 0; o >>= 1) ls += __shfl_xor(ls, o, 32);
      smf[t] = expf(m - mg) / ls;
    }
    __syncthreads();
    int d = t * 4;
    f32x4 acc = {0.f, 0.f, 0.f, 0.f};
    for (int c = 0; c < 32; ++c) {
      bf16x4v v4 = *(const bf16x4v*)((const __bf16*)pu +
                                     (size_t)((b * 32 + c) * 16 + h) * ND + d);
      f32x4 v = {(float)v4[0], (float)v4[1], (float)v4[2], (float)v4[3]};
      acc += smf[c] * v;
    }
    bf16x4v o;
#pragma unroll
    for (int j = 0; j < 4; ++j) o[j] = (__bf16)acc[j];
    *(bf16x4v*)((__bf16*)u_bf + (size_t)(b * 16 + h) * ND + d) = o;
  }
  gbar(&bar[0 * 32], &bar[256 + 0 * 32], 256);

  // ======== phase ZAX: z-tile via MFMA into LDS, + cvec, then ·Wv -> attn_x ========
  {
    int h = blk >> 4, d0 = (blk & 15) * 64;
    float* vb = smf;  // [16][68]
    const __hip_bfloat16* ub = u_bf + (size_t)(l15 * 16 + h) * ND;
    const __hip_bfloat16* wb = wvpt + (size_t)(d0 + wv * 16 + l15) * ND;
    f32x4 acc = {0.f, 0.f, 0.f, 0.f};
    for (int ks = 0; ks < 32; ++ks) {
      int d = ks * 32 + g4 * 8;
      bf16x8 a = *(const bf16x8*)(ub + d);
      bf16x8 bb = *(const bf16x8*)(wb + d);
      acc = __builtin_amdgcn_mfma_f32_16x16x32_bf16(a, bb, acc, 0, 0, 0);
    }
#pragma unroll
    for (int r = 0; r < 4; ++r) {
      int b = g4 * 4 + r;
      int nn = wv * 16 + l15;
      vb[b * 68 + nn] = acc[r] + cvec[(size_t)b * ND + d0 + nn];
    }
    __syncthreads();
    int joff = t & 63, bg = t >> 6;
    int j = h * 64 + joff;
    float ax[4] = {0.f, 0.f, 0.f, 0.f};
    for (int dd = 0; dd < 64; ++dd) {
      float wv_ = Wv[(size_t)(d0 + dd) * ND + j];
#pragma unroll
      for (int q = 0; q < 4; ++q) ax[q] += wv_ * vb[(bg * 4 + q) * 68 + dd];
    }
#pragma unroll
    for (int q = 0; q < 4; ++q) {
      float val = ax[q];
      if ((blk & 15) == 0) val += bv[j];
      atomicAdd(&attn_x[(size_t)(bg * 4 + q) * ND + j], val);
    }
  }
  gbar(&bar[1 * 32], &bar[256 + 1 * 32], 256);

  // ======== phase R1: r1 = query + attn_x@Wo + bo (256 blocks: 8 j x 32 d-chunks) ========
  {
    int j0 = (blk & 7) * 128;
    int dc = blk >> 3;  // 0..31
    int d0 = dc * 32;
    float* ax = smf;  // [16][36]
    if (t < 128) {
      int lin = t * 4;
      int bb = lin >> 5, dd = lin & 31;
      *(float4*)&ax[bb * 36 + dd] = *(const float4*)(attn_x + (size_t)bb * ND + d0 + dd);
    }
    __syncthreads();
    int joff = t & 127, bg = t >> 7;
    int j = j0 + joff;
    float acc[8];
#pragma unroll
    for (int q = 0; q < 8; ++q) acc[q] = 0.f;
    for (int dd = 0; dd < 32; ++dd) {
      float wv_ = Wo[(size_t)(d0 + dd) * ND + j];
#pragma unroll
      for (int q = 0; q < 8; ++q) acc[q] += wv_ * ax[(bg * 8 + q) * 36 + dd];
    }
#pragma unroll
    for (int q = 0; q < 8; ++q) {
      int bb = bg * 8 + q;
      float val = acc[q];
      if (dc == 0) val += bo[j] + query[(size_t)bb * ND + j];
      atomicAdd(&r1[(size_t)bb * ND + j], val);
    }
  }
  gbar(&bar[2 * 32], &bar[256 + 2 * 32], 256);

  // ======== phase FF1: h1 = LN1(r1)@W1 (256 blocks: 8 n x 32 d-chunks) ========
  {
    int n = (blk & 7) * 256 + t;
    int d0 = (blk >> 3) * 32;
    float* xs = smf;           // [16][36] = 576
    float* mv_s = smf + 1984;
    float* iv_s = smf + 2000;
    {
      int row = t >> 4, seg = t & 15;
      float s = 0.f, s2 = 0.f;
      const float* rp = r1 + (size_t)row * ND + seg * 64;
      for (int q = 0; q < 16; ++q) {
        float4 v = *(const float4*)(rp + q * 4);
        s += v.x + v.y + v.z + v.w;
        s2 += v.x * v.x + v.y * v.y + v.z * v.z + v.w * v.w;
      }
      for (int o = 1; o < 16; o <<= 1) {
        s += __shfl_xor(s, o, 16);
        s2 += __shfl_xor(s2, o, 16);
      }
      if (seg == 0) {
        float mean = s * (1.f / ND);
        float var = s2 * (1.f / ND) - mean * mean;
        mv_s[row] = mean;
        iv_s[row] = rsqrtf(var + 1e-5f);
      }
    }
    __syncthreads();
    if (t < 128) {
      int e = t * 4;
      int bb = e >> 5, dd = e & 31;
      float4 v = *(const float4*)(r1 + (size_t)bb * ND + d0 + dd);
      float4 g = *(const float4*)(g1 + d0 + dd);
      float4 be = *(const float4*)(be1 + d0 + dd);
      float m = mv_s[bb], iv = iv_s[bb];
      xs[bb * 36 + dd] = (v.x - m) * iv * g.x + be.x;
      xs[bb * 36 + dd + 1] = (v.y - m) * iv * g.y + be.y;
      xs[bb * 36 + dd + 2] = (v.z - m) * iv * g.z + be.z;
      xs[bb * 36 + dd + 3] = (v.w - m) * iv * g.w + be.w;
    }
    __syncthreads();
    float acc[16];
#pragma unroll
    for (int q = 0; q < 16; ++q) acc[q] = 0.f;
    for (int dd = 0; dd < 32; ++dd) {
      float wv_ = W1[(size_t)(d0 + dd) * NFF + n];
#pragma unroll
      for (int q = 0; q < 16; ++q) acc[q] += wv_ * xs[q * 36 + dd];
    }
#pragma unroll
    for (int q = 0; q < 16; ++q) atomicAdd(&h1[(size_t)q * NFF + n], acc[q]);
  }
  gbar(&bar[3 * 32], &bar[256 + 3 * 32], 256);

  // ======== phase FF2: out2 = relu(h1+b1)@W2 (256 blocks: 8 j x 32 n-chunks) ========
  {
    int j0 = (blk & 7) * 128;
    int n0 = (blk >> 3) * 64;
    float* hs = smf;  // [16][68]
    {
      int lin = t * 4;
      int bb = lin >> 6, nn = lin & 63;
      float4 hv = *(const float4*)(h1 + (size_t)bb * NFF + n0 + nn);
      float4 bb1 = *(const float4*)(b1 + n0 + nn);
      hs[bb * 68 + nn] = fmaxf(hv.x + bb1.x, 0.f);
      hs[bb * 68 + nn + 1] = fmaxf(hv.y + bb1.y, 0.f);
      hs[bb * 68 + nn + 2] = fmaxf(hv.z + bb1.z, 0.f);
      hs[bb * 68 + nn + 3] = fmaxf(hv.w + bb1.w, 0.f);
    }
    __syncthreads();
    int joff = t & 127, bg = t >> 7;
    int j = j0 + joff;
    float acc[8];
#pragma unroll
    for (int q = 0; q < 8; ++q) acc[q] = 0.f;
    for (int nn = 0; nn < 64; ++nn) {
      float wv_ = W2[(size_t)(n0 + nn) * ND + j];
#pragma unroll
      for (int q = 0; q < 8; ++q) acc[q] += wv_ * hs[(bg * 8 + q) * 68 + nn];
    }
#pragma unroll
    for (int q = 0; q < 8; ++q) atomicAdd(&out2[(size_t)(bg * 8 + q) * ND + j], acc[q]);
  }
  gbar(&bar[4 * 32], &bar[256 + 4 * 32], 256);

  // ======== phase LN2: out = LN( LN1(r1) + out2 + b2 ) (blk<16) ========
  if (blk < 16) {
    int b = blk;
    float* rs = smf;
    float* rs2 = smf + 256;
    float4 v = *(const float4*)(r1 + (size_t)b * ND + t * 4);
    float s = v.x + v.y + v.z + v.w;
    float s2 = v.x * v.x + v.y * v.y + v.z * v.z + v.w * v.w;
    rs[t] = s;
    rs2[t] = s2;
    __syncthreads();
    for (int st = 128; st > 0; st >>= 1) {
      if (t < st) {
        rs[t] += rs[t + st];
        rs2[t] += rs2[t + st];
      }
      __syncthreads();
    }
    float mean = rs[0] * (1.f / ND);
    float var = rs2[0] * (1.f / ND) - mean * mean;
    float inv = rsqrtf(var + 1e-5f);
    float4 g = *(const float4*)(g1 + t * 4);
    float4 be = *(const float4*)(be1 + t * 4);
    float4 o2 = *(const float4*)(out2 + (size_t)b * ND + t * 4);
    float4 bb2 = *(const float4*)(b2 + t * 4);
    float4 v2;
    v2.x = (v.x - mean) * inv * g.x + be.x + o2.x + bb2.x;
    v2.y = (v.y - mean) * inv * g.y + be.y + o2.y + bb2.y;
    v2.z = (v.z - mean) * inv * g.z + be.z + o2.z + bb2.z;
    v2.w = (v.w - mean) * inv * g.w + be.w + o2.w + bb2.w;
    __syncthreads();
    s = v2.x + v2.y + v2.z + v2.w;
    s2 = v2.x * v2.x + v2.y * v2.y + v2.z * v2.z + v2.w * v2.w;
    rs[t] = s;
    rs2[t] = s2;
    __syncthreads();
    for (int st = 128; st > 0; st >>= 1) {
      if (t < st) {
        rs[t] += rs[t + st];
        rs2[t] += rs2[t + st];
      }
      __syncthreads();
    }
    float mean2 = rs[0] * (1.f / ND);
    float var2 = rs2[0] * (1.f / ND) - mean2 * mean2;
    float inv2 = rsqrtf(var2 + 1e-5f);
    float4 gg = *(const float4*)(g2 + t * 4);
    float4 bbe = *(const float4*)(be2 + t * 4);
    float4 o;
    o.x = (v2.x - mean2) * inv2 * gg.x + bbe.x;
    o.y = (v2.y - mean2) * inv2 * gg.y + bbe.y;
    o.z = (v2.z - mean2) * inv2 * gg.z + bbe.z;
    o.w = (v2.w - mean2) * inv2 * gg.w + bbe.w;
    *(float4*)(outp + (size_t)b * ND + t * 4) = o;
  }
}

extern "C" void kernel_launch(void* const* d_in, const int* in_sizes, int n_in,
                              void* d_out, int out_size, void* d_ws, size_t ws_size,
                              hipStream_t stream) {
  const float* query = (const float*)d_in[0];
  const float* key = (const float*)d_in[1];
  const int* mask = (const int*)d_in[2];
  const float* Wq = (const float*)d_in[3];
  const float* bq = (const float*)d_in[4];
  const float* Wk = (const float*)d_in[5];
  const float* bk = (const float*)d_in[6];
  const float* Wv = (const float*)d_in[7];
  const float* bv = (const float*)d_in[8];
  const float* Wo = (const float*)d_in[9];
  const float* bo = (const float*)d_in[10];
  const float* raw_thr = (const float*)d_in[11];
  const float* Wvp = (const float*)d_in[12];
  const float* W1 = (const float*)d_in[13];
  const float* b1 = (const float*)d_in[14];
  const float* W2 = (const float*)d_in[15];
  const float* b2 = (const float*)d_in[16];
  const float* g1 = (const float*)d_in[17];
  const float* be1 = (const float*)d_in[18];
  const float* g2 = (const float*)d_in[19];
  const float* be2 = (const float*)d_in[20];

  // workspace layout (bytes)
  const size_t OFF_QROW = 0;        // 64K (zeroed)
  const size_t OFF_C = 65536;       // 64K (zeroed)
  const size_t OFF_BAR = 131072;    // 4K  (zeroed)
  const size_t ZERO_BYTES = 135168;
  const size_t OFF_ATTNX = 135168;  // 64K (zeroed in-kernel)
  const size_t OFF_R1 = 200704;     // 64K (zeroed in-kernel)
  const size_t OFF_H1 = 266240;     // 128K (zeroed in-kernel)
  const size_t OFF_OUT2 = 397312;   // 64K (zeroed in-kernel)
  const size_t OFF_S0 = 462848;     // 1K
  const size_t OFF_MLOC = 463872;   // 32K
  const size_t OFF_LLOC = 496640;   // 32K
  const size_t OFF_TBF = 529408;    // 512K bf16
  const size_t OFF_UBF = 1053696;   // 512K bf16
  const size_t OFF_WVPT = 1577984;  // 2M bf16
  const size_t OFF_PU = 4723712;    // 16M bf16
  const size_t TOTAL = 21500928;

  if (ws_size < TOTAL) {
    k_fill<<<dim3((out_size + 255) / 256), dim3(256), 0, stream>>>((float*)d_out, out_size,
                                                                   12345.0f);
    return;
  }

  char* wsb = (char*)d_ws;
  float* Qrow = (float*)(wsb + OFF_QROW);
  float* cvec = (float*)(wsb + OFF_C);
  unsigned* bar = (unsigned*)(wsb + OFF_BAR);
  float* attn_x = (float*)(wsb + OFF_ATTNX);
  float* r1 = (float*)(wsb + OFF_R1);
  float* h1 = (float*)(wsb + OFF_H1);
  float* out2 = (float*)(wsb + OFF_OUT2);
  float* s0 = (float*)(wsb + OFF_S0);
  float* mloc = (float*)(wsb + OFF_MLOC);
  float* lloc = (float*)(wsb + OFF_LLOC);
  __hip_bfloat16* t_bf = (__hip_bfloat16*)(wsb + OFF_TBF);
  __hip_bfloat16* u_bf = (__hip_bfloat16*)(wsb + OFF_UBF);
  __hip_bfloat16* wvpt = (__hip_bfloat16*)(wsb + OFF_WVPT);
  __hip_bfloat16* pu = (__hip_bfloat16*)(wsb + OFF_PU);

  hipMemsetAsync(d_ws, 0, ZERO_BYTES, stream);

  k_pre<<<dim3(192), dim3(256), 0, stream>>>(Wq, bq, Wvp, query, Wk, bk, Qrow, cvec, wvpt,
                                             t_bf, s0, bar);
  k_flash<<<dim3(32, 16), dim3(512), 0, stream>>>(key, t_bf, s0, raw_thr, mask, pu, mloc, lloc);
  k_tail<<<dim3(256), dim3(256), 0, stream>>>(pu, mloc, lloc, u_bf, wvpt, cvec, Wv, bv,
                                              attn_x, Wo, bo, query, r1, g1, be1, W1, h1, b1,
                                              W2, out2, b2, g2, be2, (float*)d_out, bar);
}